// Round 8
// baseline (351.148 us; speedup 1.0000x reference)
//
#include <hip/hip_runtime.h>
#include <stdint.h>

#define N_NODES 50000
#define N_EDGES 625000
#define DIN 256
#define HD 128
#define LN_EPS 1e-5f
#define AGG_STRIDE 136   // 128 + 8 halves pad

typedef __attribute__((ext_vector_type(8))) short bvec8;
typedef __attribute__((ext_vector_type(4))) float fvec4;

__device__ inline float bf2f(ushort u){
  union { uint32_t u32; float f; } c; c.u32 = ((uint32_t)u) << 16; return c.f;
}
__device__ inline ushort f2bf(float f){
  union { float f; uint32_t u; } c; c.f = f;
  uint32_t u = c.u;
  return (ushort)((u + 0x7fffu + ((u >> 16) & 1u)) >> 16);
}
__device__ inline float rdany(const void* p, int i, int f32){
  return f32 ? ((const float*)p)[i] : bf2f(((const ushort*)p)[i]);
}

// ---------------- zero + dtype probe (merged) ----------------
__global__ void k_zero_probe(const ushort* __restrict__ x, int* __restrict__ flag,
                             int* cnt, int* cursor, int* total){
  if ((int)blockIdx.x == (int)gridDim.x - 1){
    __shared__ int red[256];
    int t = threadIdx.x;
    int c = 0;
    for (int j = 0; j < 8; j++){
      ushort u = x[t * 8 + j];
      int e = (u >> 7) & 0xff;
      if (e >= 0x88 || (e != 0 && e <= 0x70)) c++;
    }
    red[t] = c;
    __syncthreads();
    for (int off = 128; off > 0; off >>= 1){
      if (t < off) red[t] += red[t + off];
      __syncthreads();
    }
    if (t == 0) flag[0] = (red[0] > 100) ? 1 : 0;
    return;
  }
  int i = blockIdx.x * 256 + threadIdx.x;
  if (i < N_NODES){ cnt[i] = 0; cursor[i] = 0; }
  if (i == 0) total[0] = 0;
}

// ---------------- CSR build ----------------
__global__ void k_count(const int* __restrict__ dst, int* __restrict__ cnt){
  int e = blockIdx.x * 256 + threadIdx.x;
  if (e < N_EDGES) atomicAdd(&cnt[dst[e]], 1);
}

__global__ void k_assign(const int* __restrict__ cnt, int* __restrict__ rowstart,
                         int* __restrict__ total){
  int i = blockIdx.x * 256 + threadIdx.x;
  int lane = threadIdx.x & 63;
  int c = (i < N_NODES) ? cnt[i] : 0;
  int scan = c;
  #pragma unroll
  for (int m = 1; m < 64; m <<= 1){
    int v = __shfl_up(scan, m, 64);
    if (lane >= m) scan += v;
  }
  int wave_total = __shfl(scan, 63, 64);
  int base = 0;
  if (lane == 63) base = atomicAdd(total, wave_total);
  base = __shfl(base, 63, 64);
  if (i < N_NODES) rowstart[i] = base + scan - c;
}

__global__ void k_fill(const int* __restrict__ src, const int* __restrict__ dst,
                       const int* __restrict__ rowstart, int* __restrict__ cursor,
                       int* __restrict__ esrc){
  int e = blockIdx.x * 256 + threadIdx.x;
  if (e < N_EDGES){
    int d = dst[e];
    int pos = atomicAdd(&cursor[d], 1);
    esrc[rowstart[d] + pos] = src[e];
  }
}

// ---------------- weight prep: swizzle into MFMA fragment order ----------------
__global__ void k_prep_w(const int* __restrict__ flag,
                         const void* __restrict__ W_in,
                         const void* __restrict__ Wl1, const void* __restrict__ Wr1,
                         const void* __restrict__ Wl2, const void* __restrict__ Wr2,
                         ushort* __restrict__ WtA, ushort* __restrict__ Wc1, ushort* __restrict__ Wc2,
                         const void* b_in, const void* kind_embed, const void* ext_seed,
                         const void* bl1, const void* gammap, const void* betap,
                         const void* bl2, float* __restrict__ vecs){
  int f32 = flag[0];
  int idx = blockIdx.x * 256 + threadIdx.x;
  if (idx < 128 * 256){
    int c   = idx >> 9;
    int lam = (idx >> 3) & 63;
    int j   = idx & 7;
    int k0  = c >> 3;
    int t   = c & 7;
    int n   = t * 16 + (lam & 15);
    int k   = k0 * 32 + (lam >> 4) * 8 + j;
    WtA[idx] = f2bf(rdany(W_in, k * 128 + n, f32));
    if (k < 128){
      Wc1[idx] = f2bf(rdany(Wl1, k * 128 + n, f32));
      Wc2[idx] = f2bf(rdany(Wl2, k * 128 + n, f32));
    } else {
      Wc1[idx] = f2bf(rdany(Wr1, (k - 128) * 128 + n, f32));
      Wc2[idx] = f2bf(rdany(Wr2, (k - 128) * 128 + n, f32));
    }
  }
  if (blockIdx.x == 0){
    for (int i = threadIdx.x; i < 1152; i += 256){
      float v;
      if (i < 128)       v = rdany(b_in, i, f32);
      else if (i < 512)  v = rdany(kind_embed, i - 128, f32);
      else if (i < 640)  v = rdany(ext_seed, i - 512, f32);
      else if (i < 768)  v = rdany(bl1, i - 640, f32);
      else if (i < 896)  v = rdany(gammap, i - 768, f32);
      else if (i < 1024) v = rdany(betap, i - 896, f32);
      else               v = rdany(bl2, i - 1024, f32);
      vecs[i] = v;
    }
  }
}

// ---------------- input GEMM: 32KB half-staged LDS B ----------------
__global__ void __launch_bounds__(256) k_gemm_in(
    const int* __restrict__ flag, const void* __restrict__ xin,
    const ushort* __restrict__ WtA, const float* __restrict__ vecs,
    const int* __restrict__ node_kind, ushort* __restrict__ h0){
  __shared__ __align__(16) ushort sW[16384];   // 32 KB half-stage
  int f32 = flag[0];
  int tid  = threadIdx.x;
  int wave = tid >> 6;
  int lane = tid & 63;
  int quad = lane >> 4;
  int l16  = lane & 15;
  int rb = blockIdx.x * 64 + wave * 16;

  // half-0 weight loads to regs (fly during A-loads)
  uint4 wreg[8];
  #pragma unroll
  for (int it = 0; it < 8; it++)
    wreg[it] = *(const uint4*)(WtA + it * 2048 + tid * 8);

  int arow = rb + l16; if (arow >= N_NODES) arow = N_NODES - 1;
  const ushort* abf = (const ushort*)xin + (size_t)arow * DIN + quad * 8;
  const float*  af  = (const float*)xin + (size_t)arow * DIN + quad * 8;

  bvec8 a[8];
  if (f32){
    #pragma unroll
    for (int k0 = 0; k0 < 8; k0++){
      fvec4 lo = *(const fvec4*)(af + k0 * 32);
      fvec4 hi = *(const fvec4*)(af + k0 * 32 + 4);
      a[k0][0] = (short)f2bf(lo[0]); a[k0][1] = (short)f2bf(lo[1]);
      a[k0][2] = (short)f2bf(lo[2]); a[k0][3] = (short)f2bf(lo[3]);
      a[k0][4] = (short)f2bf(hi[0]); a[k0][5] = (short)f2bf(hi[1]);
      a[k0][6] = (short)f2bf(hi[2]); a[k0][7] = (short)f2bf(hi[3]);
    }
  } else {
    #pragma unroll
    for (int k0 = 0; k0 < 8; k0++) a[k0] = *(const bvec8*)(abf + k0 * 32);
  }

  #pragma unroll
  for (int it = 0; it < 8; it++)
    *(uint4*)(sW + it * 2048 + tid * 8) = wreg[it];
  __syncthreads();

  // half-1 loads in flight during half-0 MFMA
  #pragma unroll
  for (int it = 0; it < 8; it++)
    wreg[it] = *(const uint4*)(WtA + 16384 + it * 2048 + tid * 8);

  fvec4 acc[8];
  #pragma unroll
  for (int t = 0; t < 8; t++)
    #pragma unroll
    for (int i = 0; i < 4; i++) acc[t][i] = 0.f;

  #pragma unroll
  for (int k0 = 0; k0 < 4; k0++){
    #pragma unroll
    for (int t = 0; t < 8; t++){
      bvec8 b = *(const bvec8*)(sW + ((k0 * 8 + t) * 64 + lane) * 8);
      acc[t] = __builtin_amdgcn_mfma_f32_16x16x32_bf16(a[k0], b, acc[t], 0, 0, 0);
    }
  }
  __syncthreads();
  #pragma unroll
  for (int it = 0; it < 8; it++)
    *(uint4*)(sW + it * 2048 + tid * 8) = wreg[it];
  __syncthreads();
  #pragma unroll
  for (int k0 = 0; k0 < 4; k0++){
    #pragma unroll
    for (int t = 0; t < 8; t++){
      bvec8 b = *(const bvec8*)(sW + ((k0 * 8 + t) * 64 + lane) * 8);
      acc[t] = __builtin_amdgcn_mfma_f32_16x16x32_bf16(a[4 + k0], b, acc[t], 0, 0, 0);
    }
  }

  const float* b_in  = vecs;
  const float* kinde = vecs + 128;
  const float* ext   = vecs + 512;
  #pragma unroll
  for (int i = 0; i < 4; i++){
    int row = rb + quad * 4 + i;
    if (row >= N_NODES) continue;
    int kind = node_kind[row];
    float extf = (kind != 0) ? 1.f : 0.f;
    #pragma unroll
    for (int t = 0; t < 8; t++){
      int col = t * 16 + l16;
      float v = acc[t][i] + b_in[col] + kinde[kind * HD + col] + extf * ext[col];
      h0[(size_t)row * HD + col] = f2bf(v);
    }
  }
}

// ---------------- fused gather + conv GEMM, v2 ----------------
// Disjoint LDS regions (agg 17KB + weights 32KB = 49KB -> 3 blocks/CU).
// Weight half-0 loads issued BEFORE the gather (complete for free during it);
// half-1 loads fly during half-0 MFMA. Gather: 8 edges in flight per node.
template<int MODE>
__global__ void __launch_bounds__(256) k_conv_fused(
    const int* __restrict__ flag, const ushort* __restrict__ h,
    const int* __restrict__ rowstart, const int* __restrict__ cnt,
    const int* __restrict__ esrc,
    const ushort* __restrict__ Wc, const float* __restrict__ vecs,
    void* __restrict__ outp){
  __shared__ __align__(16) ushort sW[16384];            // 32 KB weight half-stage
  __shared__ __align__(16) ushort sAgg[64 * AGG_STRIDE]; // 17 KB agg rows
  int f32 = flag[0];
  int tid  = threadIdx.x;
  int wave = tid >> 6;
  int lane = tid & 63;
  int quad = lane >> 4;
  int l16  = lane & 15;
  int rb0 = blockIdx.x * 64;
  int rb  = rb0 + wave * 16;

  // weight half-0 -> regs (in flight through the whole gather)
  uint4 wreg[8];
  #pragma unroll
  for (int it = 0; it < 8; it++)
    wreg[it] = *(const uint4*)(Wc + it * 2048 + tid * 8);

  // self-row (h/Wr-half) A-frags
  int arow = rb + l16; if (arow >= N_NODES) arow = N_NODES - 1;
  const ushort* hb = h + (size_t)arow * HD + quad * 8;
  bvec8 a[8];
  #pragma unroll
  for (int j = 0; j < 4; j++) a[4 + j] = *(const bvec8*)(hb + j * 32);

  // ---- gather: 4 rounds x 4 nodes/wave, 8 edges in flight ----
  #pragma unroll
  for (int r = 0; r < 4; r++){
    int nd = wave * 16 + r * 4 + quad;
    int n  = rb0 + nd;
    bool valid = n < N_NODES;
    int b   = valid ? rowstart[n] : 0;
    int deg = valid ? cnt[n] : 0;
    int e   = b + deg;
    float acc8[8];
    #pragma unroll
    for (int j = 0; j < 8; j++) acc8[j] = 0.f;
    for (int i = b; i < e; i += 8){
      int ss[8];
      #pragma unroll
      for (int j = 0; j < 8; j++){
        int ij = i + j;
        ss[j] = esrc[(ij < e) ? ij : i];
      }
      uint4 p[8];
      #pragma unroll
      for (int j = 0; j < 8; j++){
        if (i + j < e) p[j] = *(const uint4*)(h + (size_t)ss[j] * HD + l16 * 8);
        else           p[j] = (uint4){0, 0, 0, 0};
      }
      #pragma unroll
      for (int j = 0; j < 8; j++){
        const uint32_t* w = (const uint32_t*)&p[j];
        #pragma unroll
        for (int q = 0; q < 4; q++){
          acc8[2 * q]     += bf2f((ushort)(w[q] & 0xffffu));
          acc8[2 * q + 1] += bf2f((ushort)(w[q] >> 16));
        }
      }
    }
    float scale = (deg > 0) ? 1.f / (float)deg : 0.f;
    ushort* dstp = sAgg + nd * AGG_STRIDE + l16 * 8;
    #pragma unroll
    for (int j = 0; j < 8; j++) dstp[j] = f2bf(acc8[j] * scale);
  }

  // commit weight half-0 (loads finished long ago)
  #pragma unroll
  for (int it = 0; it < 8; it++)
    *(uint4*)(sW + it * 2048 + tid * 8) = wreg[it];
  __syncthreads();

  // agg A-frags (rows written by this same wave; barrier above also covers it)
  {
    int nd = wave * 16 + l16;
    const ushort* ap = sAgg + nd * AGG_STRIDE + quad * 8;
    #pragma unroll
    for (int j = 0; j < 4; j++) a[j] = *(const bvec8*)(ap + j * 32);
  }

  // half-1 loads fly during half-0 MFMA
  #pragma unroll
  for (int it = 0; it < 8; it++)
    wreg[it] = *(const uint4*)(Wc + 16384 + it * 2048 + tid * 8);

  fvec4 acc[8];
  #pragma unroll
  for (int t = 0; t < 8; t++)
    #pragma unroll
    for (int i = 0; i < 4; i++) acc[t][i] = 0.f;

  #pragma unroll
  for (int k0 = 0; k0 < 4; k0++){
    #pragma unroll
    for (int t = 0; t < 8; t++){
      bvec8 b = *(const bvec8*)(sW + ((k0 * 8 + t) * 64 + lane) * 8);
      acc[t] = __builtin_amdgcn_mfma_f32_16x16x32_bf16(a[k0], b, acc[t], 0, 0, 0);
    }
  }
  __syncthreads();
  #pragma unroll
  for (int it = 0; it < 8; it++)
    *(uint4*)(sW + it * 2048 + tid * 8) = wreg[it];
  __syncthreads();
  #pragma unroll
  for (int k0 = 0; k0 < 4; k0++){
    #pragma unroll
    for (int t = 0; t < 8; t++){
      bvec8 b = *(const bvec8*)(sW + ((k0 * 8 + t) * 64 + lane) * 8);
      acc[t] = __builtin_amdgcn_mfma_f32_16x16x32_bf16(a[4 + k0], b, acc[t], 0, 0, 0);
    }
  }

  if (MODE == 1){
    const float* bias   = vecs + 640;
    const float* gammav = vecs + 768;
    const float* betav  = vecs + 896;
    float zv[8][4];
    float s1[4] = {0.f, 0.f, 0.f, 0.f};
    float s2[4] = {0.f, 0.f, 0.f, 0.f};
    #pragma unroll
    for (int t = 0; t < 8; t++){
      float bc = bias[t * 16 + l16];
      #pragma unroll
      for (int i = 0; i < 4; i++){
        float v = acc[t][i] + bc;
        zv[t][i] = v;
        s1[i] += v;
        s2[i] += v * v;
      }
    }
    #pragma unroll
    for (int m = 1; m < 16; m <<= 1){
      #pragma unroll
      for (int i = 0; i < 4; i++){
        s1[i] += __shfl_xor(s1[i], m, 64);
        s2[i] += __shfl_xor(s2[i], m, 64);
      }
    }
    float mu[4], rs[4];
    #pragma unroll
    for (int i = 0; i < 4; i++){
      mu[i] = s1[i] * (1.f / 128.f);
      float var = s2[i] * (1.f / 128.f) - mu[i] * mu[i];
      rs[i] = rsqrtf(var + LN_EPS);
    }
    ushort* ob = (ushort*)outp;
    #pragma unroll
    for (int t = 0; t < 8; t++){
      int col = t * 16 + l16;
      float g = gammav[col], bt = betav[col];
      #pragma unroll
      for (int i = 0; i < 4; i++){
        int row = rb + quad * 4 + i;
        if (row >= N_NODES) continue;
        float v = (zv[t][i] - mu[i]) * rs[i] * g + bt;
        v = fmaxf(v, 0.f);
        ob[(size_t)row * HD + col] = f2bf(v);
      }
    }
  } else {
    const float* bias = vecs + 1024;
    #pragma unroll
    for (int t = 0; t < 8; t++){
      int col = t * 16 + l16;
      float bc = bias[col];
      #pragma unroll
      for (int i = 0; i < 4; i++){
        int row = rb + quad * 4 + i;
        if (row >= N_NODES) continue;
        float v = acc[t][i] + bc;
        if (f32) ((float*)outp)[(size_t)row * HD + col] = v;
        else     ((ushort*)outp)[(size_t)row * HD + col] = f2bf(v);
      }
    }
  }
}

extern "C" void kernel_launch(void* const* d_in, const int* in_sizes, int n_in,
                              void* d_out, int out_size, void* d_ws, size_t ws_size,
                              hipStream_t stream) {
  const void* x          = d_in[0];
  const int*  ei         = (const int*)d_in[1];
  const int*  node_kind  = (const int*)d_in[2];
  const void* W_in       = d_in[3];
  const void* b_in       = d_in[4];
  const void* kind_embed = d_in[5];
  const void* ext_seed   = d_in[6];
  const void* Wl1        = d_in[7];
  const void* bl1        = d_in[8];
  const void* Wr1        = d_in[9];
  const void* gammap     = d_in[10];
  const void* betap      = d_in[11];
  const void* Wl2        = d_in[12];
  const void* bl2        = d_in[13];
  const void* Wr2        = d_in[14];
  const int* src = ei;
  const int* dst = ei + N_EDGES;

  char* ws = (char*)d_ws;
  size_t off = 0;
  auto alloc = [&](size_t bytes) -> void* {
    void* p = ws + off;
    off += (bytes + 255) & ~(size_t)255;
    return p;
  };
  int*    flag     = (int*)alloc(256);
  int*    total    = (int*)alloc(256);
  int*    cnt      = (int*)alloc(N_NODES * 4);
  int*    cursor   = (int*)alloc(N_NODES * 4);
  int*    rowstart = (int*)alloc(N_NODES * 4);
  int*    esrc     = (int*)alloc(N_EDGES * 4);
  ushort* WtA      = (ushort*)alloc(128 * 256 * 2);
  ushort* Wc1      = (ushort*)alloc(128 * 256 * 2);
  ushort* Wc2      = (ushort*)alloc(128 * 256 * 2);
  float*  vecs     = (float*)alloc(1152 * 4);
  ushort* h0       = (ushort*)alloc((size_t)N_NODES * HD * 2);
  ushort* h1       = (ushort*)alloc((size_t)N_NODES * HD * 2);

  k_zero_probe<<<(N_NODES + 255) / 256 + 1, 256, 0, stream>>>((const ushort*)x, flag, cnt, cursor, total);
  k_prep_w<<<(128 * 256 + 255) / 256, 256, 0, stream>>>(flag, W_in, Wl1, Wr1, Wl2, Wr2, WtA, Wc1, Wc2,
                                                        b_in, kind_embed, ext_seed, bl1, gammap, betap, bl2, vecs);
  k_count<<<(N_EDGES + 255) / 256, 256, 0, stream>>>(dst, cnt);
  k_assign<<<(N_NODES + 255) / 256, 256, 0, stream>>>(cnt, rowstart, total);
  k_fill<<<(N_EDGES + 255) / 256, 256, 0, stream>>>(src, dst, rowstart, cursor, esrc);

  int gemm_grid = (N_NODES + 63) / 64;
  k_gemm_in<<<gemm_grid, 256, 0, stream>>>(flag, x, WtA, vecs, node_kind, h0);
  k_conv_fused<1><<<gemm_grid, 256, 0, stream>>>(flag, h0, rowstart, cnt, esrc, Wc1, vecs, (void*)h1);
  k_conv_fused<2><<<gemm_grid, 256, 0, stream>>>(flag, h1, rowstart, cnt, esrc, Wc2, vecs, d_out);
}

// Round 9
// 295.089 us; speedup vs baseline: 1.1900x; 1.1900x over previous
//
#include <hip/hip_runtime.h>
#include <stdint.h>

#define N_NODES 50000
#define N_EDGES 625000
#define DIN 256
#define HD 128
#define LN_EPS 1e-5f
#define AGG_STRIDE 136   // 128 + 8 halves pad

typedef __attribute__((ext_vector_type(8))) short bvec8;
typedef __attribute__((ext_vector_type(4))) float fvec4;

__device__ inline float bf2f(ushort u){
  union { uint32_t u32; float f; } c; c.u32 = ((uint32_t)u) << 16; return c.f;
}
__device__ inline ushort f2bf(float f){
  union { float f; uint32_t u; } c; c.f = f;
  uint32_t u = c.u;
  return (ushort)((u + 0x7fffu + ((u >> 16) & 1u)) >> 16);
}
__device__ inline float rdany(const void* p, int i, int f32){
  return f32 ? ((const float*)p)[i] : bf2f(((const ushort*)p)[i]);
}

// ---------------- zero + dtype probe (merged) ----------------
__global__ void k_zero_probe(const ushort* __restrict__ x, int* __restrict__ flag,
                             int* cnt, int* cursor, int* total){
  if ((int)blockIdx.x == (int)gridDim.x - 1){
    __shared__ int red[256];
    int t = threadIdx.x;
    int c = 0;
    for (int j = 0; j < 8; j++){
      ushort u = x[t * 8 + j];
      int e = (u >> 7) & 0xff;
      if (e >= 0x88 || (e != 0 && e <= 0x70)) c++;
    }
    red[t] = c;
    __syncthreads();
    for (int off = 128; off > 0; off >>= 1){
      if (t < off) red[t] += red[t + off];
      __syncthreads();
    }
    if (t == 0) flag[0] = (red[0] > 100) ? 1 : 0;
    return;
  }
  int i = blockIdx.x * 256 + threadIdx.x;
  if (i < N_NODES){ cnt[i] = 0; cursor[i] = 0; }
  if (i == 0) total[0] = 0;
}

// ---------------- CSR build ----------------
__global__ void k_count(const int* __restrict__ dst, int* __restrict__ cnt){
  int e = blockIdx.x * 256 + threadIdx.x;
  if (e < N_EDGES) atomicAdd(&cnt[dst[e]], 1);
}

__global__ void k_assign(const int* __restrict__ cnt, int* __restrict__ rowstart,
                         int* __restrict__ total){
  int i = blockIdx.x * 256 + threadIdx.x;
  int lane = threadIdx.x & 63;
  int c = (i < N_NODES) ? cnt[i] : 0;
  int scan = c;
  #pragma unroll
  for (int m = 1; m < 64; m <<= 1){
    int v = __shfl_up(scan, m, 64);
    if (lane >= m) scan += v;
  }
  int wave_total = __shfl(scan, 63, 64);
  int base = 0;
  if (lane == 63) base = atomicAdd(total, wave_total);
  base = __shfl(base, 63, 64);
  if (i < N_NODES) rowstart[i] = base + scan - c;
}

__global__ void k_fill(const int* __restrict__ src, const int* __restrict__ dst,
                       const int* __restrict__ rowstart, int* __restrict__ cursor,
                       int* __restrict__ esrc){
  int e = blockIdx.x * 256 + threadIdx.x;
  if (e < N_EDGES){
    int d = dst[e];
    int pos = atomicAdd(&cursor[d], 1);
    esrc[rowstart[d] + pos] = src[e];
  }
}

// ---------------- weight prep: swizzle into MFMA fragment order ----------------
__global__ void k_prep_w(const int* __restrict__ flag,
                         const void* __restrict__ W_in,
                         const void* __restrict__ Wl1, const void* __restrict__ Wr1,
                         const void* __restrict__ Wl2, const void* __restrict__ Wr2,
                         ushort* __restrict__ WtA, ushort* __restrict__ Wc1, ushort* __restrict__ Wc2,
                         const void* b_in, const void* kind_embed, const void* ext_seed,
                         const void* bl1, const void* gammap, const void* betap,
                         const void* bl2, float* __restrict__ vecs){
  int f32 = flag[0];
  int idx = blockIdx.x * 256 + threadIdx.x;
  if (idx < 128 * 256){
    int c   = idx >> 9;
    int lam = (idx >> 3) & 63;
    int j   = idx & 7;
    int k0  = c >> 3;
    int t   = c & 7;
    int n   = t * 16 + (lam & 15);
    int k   = k0 * 32 + (lam >> 4) * 8 + j;
    WtA[idx] = f2bf(rdany(W_in, k * 128 + n, f32));
    if (k < 128){
      Wc1[idx] = f2bf(rdany(Wl1, k * 128 + n, f32));
      Wc2[idx] = f2bf(rdany(Wl2, k * 128 + n, f32));
    } else {
      Wc1[idx] = f2bf(rdany(Wr1, (k - 128) * 128 + n, f32));
      Wc2[idx] = f2bf(rdany(Wr2, (k - 128) * 128 + n, f32));
    }
  }
  if (blockIdx.x == 0){
    for (int i = threadIdx.x; i < 1152; i += 256){
      float v;
      if (i < 128)       v = rdany(b_in, i, f32);
      else if (i < 512)  v = rdany(kind_embed, i - 128, f32);
      else if (i < 640)  v = rdany(ext_seed, i - 512, f32);
      else if (i < 768)  v = rdany(bl1, i - 640, f32);
      else if (i < 896)  v = rdany(gammap, i - 768, f32);
      else if (i < 1024) v = rdany(betap, i - 896, f32);
      else               v = rdany(bl2, i - 1024, f32);
      vecs[i] = v;
    }
  }
}

// ---------------- input GEMM: LDS-staged B (R6 version, known-good) ----------------
__global__ void __launch_bounds__(256) k_gemm_in(
    const int* __restrict__ flag, const void* __restrict__ xin,
    const ushort* __restrict__ WtA, const float* __restrict__ vecs,
    const int* __restrict__ node_kind, ushort* __restrict__ h0){
  __shared__ __align__(16) ushort sW[128 * 256];
  int f32 = flag[0];
  int tid  = threadIdx.x;
  int wave = tid >> 6;
  int lane = tid & 63;
  int quad = lane >> 4;
  int l16  = lane & 15;
  int rb = blockIdx.x * 64 + wave * 16;

  fvec4 acc[8];
  #pragma unroll
  for (int t = 0; t < 8; t++)
    #pragma unroll
    for (int i = 0; i < 4; i++) acc[t][i] = 0.f;

  int arow = rb + l16; if (arow >= N_NODES) arow = N_NODES - 1;
  const ushort* abf = (const ushort*)xin + (size_t)arow * DIN + quad * 8;
  const float*  af  = (const float*)xin + (size_t)arow * DIN + quad * 8;

  bvec8 a[8];
  if (f32){
    #pragma unroll
    for (int k0 = 0; k0 < 8; k0++){
      fvec4 lo = *(const fvec4*)(af + k0 * 32);
      fvec4 hi = *(const fvec4*)(af + k0 * 32 + 4);
      a[k0][0] = (short)f2bf(lo[0]); a[k0][1] = (short)f2bf(lo[1]);
      a[k0][2] = (short)f2bf(lo[2]); a[k0][3] = (short)f2bf(lo[3]);
      a[k0][4] = (short)f2bf(hi[0]); a[k0][5] = (short)f2bf(hi[1]);
      a[k0][6] = (short)f2bf(hi[2]); a[k0][7] = (short)f2bf(hi[3]);
    }
  } else {
    #pragma unroll
    for (int k0 = 0; k0 < 8; k0++) a[k0] = *(const bvec8*)(abf + k0 * 32);
  }

  #pragma unroll
  for (int it = 0; it < 16; it++){
    int off = it * 2048 + tid * 8;
    *(uint4*)(sW + off) = *(const uint4*)(WtA + off);
  }
  __syncthreads();

  #pragma unroll
  for (int k0 = 0; k0 < 8; k0++){
    #pragma unroll
    for (int t = 0; t < 8; t++){
      bvec8 b = *(const bvec8*)(sW + ((k0 * 8 + t) * 64 + lane) * 8);
      acc[t] = __builtin_amdgcn_mfma_f32_16x16x32_bf16(a[k0], b, acc[t], 0, 0, 0);
    }
  }

  const float* b_in  = vecs;
  const float* kinde = vecs + 128;
  const float* ext   = vecs + 512;
  #pragma unroll
  for (int i = 0; i < 4; i++){
    int row = rb + quad * 4 + i;
    if (row >= N_NODES) continue;
    int kind = node_kind[row];
    float extf = (kind != 0) ? 1.f : 0.f;
    #pragma unroll
    for (int t = 0; t < 8; t++){
      int col = t * 16 + l16;
      float v = acc[t][i] + b_in[col] + kinde[kind * HD + col] + extf * ext[col];
      h0[(size_t)row * HD + col] = f2bf(v);
    }
  }
}

// ---------------- fused gather + conv GEMM, v3 ----------------
// R6-v1 structure (32KB shared sbuf, weights staged after gather), but gather
// runs 8 edges in flight per node; self-row A-frags load AFTER the gather so
// the gather phase carries minimal register liveness (no spill).
template<int MODE>
__global__ void __launch_bounds__(256) k_conv_fused(
    const int* __restrict__ flag, const ushort* __restrict__ h,
    const int* __restrict__ rowstart, const int* __restrict__ cnt,
    const int* __restrict__ esrc,
    const ushort* __restrict__ Wc, const float* __restrict__ vecs,
    void* __restrict__ outp){
  __shared__ __align__(16) ushort sbuf[16384];   // 32 KB: agg rows, then weight half-stages
  int f32 = flag[0];
  int tid  = threadIdx.x;
  int wave = tid >> 6;
  int lane = tid & 63;
  int quad = lane >> 4;
  int l16  = lane & 15;
  int rb0 = blockIdx.x * 64;
  int rb  = rb0 + wave * 16;

  // ---- phase 1: gather agg rows into LDS, 8 edges in flight per node ----
  #pragma unroll
  for (int r = 0; r < 4; r++){
    int nd = wave * 16 + r * 4 + quad;
    int n  = rb0 + nd;
    bool valid = n < N_NODES;
    int b   = valid ? rowstart[n] : 0;
    int deg = valid ? cnt[n] : 0;
    int e   = b + deg;
    float acc8[8];
    #pragma unroll
    for (int j = 0; j < 8; j++) acc8[j] = 0.f;
    for (int i = b; i < e; i += 8){
      int ss[8];
      #pragma unroll
      for (int j = 0; j < 8; j++){
        int ij = i + j;
        ss[j] = esrc[(ij < e) ? ij : i];
      }
      uint4 p[8];
      #pragma unroll
      for (int j = 0; j < 8; j++){
        p[j] = (uint4){0, 0, 0, 0};
        if (i + j < e) p[j] = *(const uint4*)(h + (size_t)ss[j] * HD + l16 * 8);
      }
      #pragma unroll
      for (int j = 0; j < 8; j++){
        const uint32_t* w = (const uint32_t*)&p[j];
        #pragma unroll
        for (int q = 0; q < 4; q++){
          acc8[2 * q]     += bf2f((ushort)(w[q] & 0xffffu));
          acc8[2 * q + 1] += bf2f((ushort)(w[q] >> 16));
        }
      }
    }
    float scale = (deg > 0) ? 1.f / (float)deg : 0.f;
    ushort* dstp = sbuf + nd * AGG_STRIDE + l16 * 8;
    #pragma unroll
    for (int j = 0; j < 8; j++) dstp[j] = f2bf(acc8[j] * scale);
  }

  // self-row (h/Wr-half) A-frags — after the gather, overlap with weight staging
  int arow = rb + l16; if (arow >= N_NODES) arow = N_NODES - 1;
  const ushort* hb = h + (size_t)arow * HD + quad * 8;
  bvec8 a[8];
  #pragma unroll
  for (int j = 0; j < 4; j++) a[4 + j] = *(const bvec8*)(hb + j * 32);

  __syncthreads();

  // agg A-frags from LDS
  {
    int nd = wave * 16 + l16;
    const ushort* ap = sbuf + nd * AGG_STRIDE + quad * 8;
    #pragma unroll
    for (int j = 0; j < 4; j++) a[j] = *(const bvec8*)(ap + j * 32);
  }
  __syncthreads();   // everyone done reading agg before overwrite

  fvec4 acc[8];
  #pragma unroll
  for (int t = 0; t < 8; t++)
    #pragma unroll
    for (int i = 0; i < 4; i++) acc[t][i] = 0.f;

  // ---- weights in two 32KB half-stages over the same LDS ----
  #pragma unroll
  for (int s = 0; s < 2; s++){
    #pragma unroll
    for (int it = 0; it < 8; it++){
      int off = it * 2048 + tid * 8;
      *(uint4*)(sbuf + off) = *(const uint4*)(Wc + s * 16384 + off);
    }
    __syncthreads();
    #pragma unroll
    for (int k0 = 0; k0 < 4; k0++){
      #pragma unroll
      for (int t = 0; t < 8; t++){
        bvec8 b = *(const bvec8*)(sbuf + ((k0 * 8 + t) * 64 + lane) * 8);
        acc[t] = __builtin_amdgcn_mfma_f32_16x16x32_bf16(a[s * 4 + k0], b, acc[t], 0, 0, 0);
      }
    }
    __syncthreads();
  }

  if (MODE == 1){
    const float* bias   = vecs + 640;
    const float* gammav = vecs + 768;
    const float* betav  = vecs + 896;
    float zv[8][4];
    float s1[4] = {0.f, 0.f, 0.f, 0.f};
    float s2[4] = {0.f, 0.f, 0.f, 0.f};
    #pragma unroll
    for (int t = 0; t < 8; t++){
      float bc = bias[t * 16 + l16];
      #pragma unroll
      for (int i = 0; i < 4; i++){
        float v = acc[t][i] + bc;
        zv[t][i] = v;
        s1[i] += v;
        s2[i] += v * v;
      }
    }
    #pragma unroll
    for (int m = 1; m < 16; m <<= 1){
      #pragma unroll
      for (int i = 0; i < 4; i++){
        s1[i] += __shfl_xor(s1[i], m, 64);
        s2[i] += __shfl_xor(s2[i], m, 64);
      }
    }
    float mu[4], rs[4];
    #pragma unroll
    for (int i = 0; i < 4; i++){
      mu[i] = s1[i] * (1.f / 128.f);
      float var = s2[i] * (1.f / 128.f) - mu[i] * mu[i];
      rs[i] = rsqrtf(var + LN_EPS);
    }
    ushort* ob = (ushort*)outp;
    #pragma unroll
    for (int t = 0; t < 8; t++){
      int col = t * 16 + l16;
      float g = gammav[col], bt = betav[col];
      #pragma unroll
      for (int i = 0; i < 4; i++){
        int row = rb + quad * 4 + i;
        if (row >= N_NODES) continue;
        float v = (zv[t][i] - mu[i]) * rs[i] * g + bt;
        v = fmaxf(v, 0.f);
        ob[(size_t)row * HD + col] = f2bf(v);
      }
    }
  } else {
    const float* bias = vecs + 1024;
    #pragma unroll
    for (int t = 0; t < 8; t++){
      int col = t * 16 + l16;
      float bc = bias[col];
      #pragma unroll
      for (int i = 0; i < 4; i++){
        int row = rb + quad * 4 + i;
        if (row >= N_NODES) continue;
        float v = acc[t][i] + bc;
        if (f32) ((float*)outp)[(size_t)row * HD + col] = v;
        else     ((ushort*)outp)[(size_t)row * HD + col] = f2bf(v);
      }
    }
  }
}

extern "C" void kernel_launch(void* const* d_in, const int* in_sizes, int n_in,
                              void* d_out, int out_size, void* d_ws, size_t ws_size,
                              hipStream_t stream) {
  const void* x          = d_in[0];
  const int*  ei         = (const int*)d_in[1];
  const int*  node_kind  = (const int*)d_in[2];
  const void* W_in       = d_in[3];
  const void* b_in       = d_in[4];
  const void* kind_embed = d_in[5];
  const void* ext_seed   = d_in[6];
  const void* Wl1        = d_in[7];
  const void* bl1        = d_in[8];
  const void* Wr1        = d_in[9];
  const void* gammap     = d_in[10];
  const void* betap      = d_in[11];
  const void* Wl2        = d_in[12];
  const void* bl2        = d_in[13];
  const void* Wr2        = d_in[14];
  const int* src = ei;
  const int* dst = ei + N_EDGES;

  char* ws = (char*)d_ws;
  size_t off = 0;
  auto alloc = [&](size_t bytes) -> void* {
    void* p = ws + off;
    off += (bytes + 255) & ~(size_t)255;
    return p;
  };
  int*    flag     = (int*)alloc(256);
  int*    total    = (int*)alloc(256);
  int*    cnt      = (int*)alloc(N_NODES * 4);
  int*    cursor   = (int*)alloc(N_NODES * 4);
  int*    rowstart = (int*)alloc(N_NODES * 4);
  int*    esrc     = (int*)alloc(N_EDGES * 4);
  ushort* WtA      = (ushort*)alloc(128 * 256 * 2);
  ushort* Wc1      = (ushort*)alloc(128 * 256 * 2);
  ushort* Wc2      = (ushort*)alloc(128 * 256 * 2);
  float*  vecs     = (float*)alloc(1152 * 4);
  ushort* h0       = (ushort*)alloc((size_t)N_NODES * HD * 2);
  ushort* h1       = (ushort*)alloc((size_t)N_NODES * HD * 2);

  k_zero_probe<<<(N_NODES + 255) / 256 + 1, 256, 0, stream>>>((const ushort*)x, flag, cnt, cursor, total);
  k_prep_w<<<(128 * 256 + 255) / 256, 256, 0, stream>>>(flag, W_in, Wl1, Wr1, Wl2, Wr2, WtA, Wc1, Wc2,
                                                        b_in, kind_embed, ext_seed, bl1, gammap, betap, bl2, vecs);
  k_count<<<(N_EDGES + 255) / 256, 256, 0, stream>>>(dst, cnt);
  k_assign<<<(N_NODES + 255) / 256, 256, 0, stream>>>(cnt, rowstart, total);
  k_fill<<<(N_EDGES + 255) / 256, 256, 0, stream>>>(src, dst, rowstart, cursor, esrc);

  int gemm_grid = (N_NODES + 63) / 64;
  k_gemm_in<<<gemm_grid, 256, 0, stream>>>(flag, x, WtA, vecs, node_kind, h0);
  k_conv_fused<1><<<gemm_grid, 256, 0, stream>>>(flag, h0, rowstart, cnt, esrc, Wc1, vecs, (void*)h1);
  k_conv_fused<2><<<gemm_grid, 256, 0, stream>>>(flag, h1, rowstart, cnt, esrc, Wc2, vecs, d_out);
}